// Round 3
// baseline (4248.687 us; speedup 1.0000x reference)
//
#include <hip/hip_runtime.h>

// ADI diffusion: 2048 images of 128x128 fp32, 10 steps of (x half, y full,
// x half) tridiagonal solves. Factorizations precomputed per substep into
// g_FG by factor_kernel.
//
// R3: stash-free in-register transpose. R2's half-buffer transpose needed a
// 64-float stash -> pressure ~260 under launch_bounds(128,2) -> compiler
// split 128 arch VGPR + AGPRs (v_accvgpr traffic) + 43 MB scratch -> 464 us.
// New transpose: two 64x68 LDS tiles (34 KB). Step 1: each wave transposes
// its diagonal 64x64 block through its own tile (write 64, read 64 into the
// freed slots - exact fit). Step 2: waves exchange off-diagonal blocks the
// same way (W0 writes B to its tile, W1 writes C; cross-read). Peak regs =
// 128 + working ~ 180, no stash, no AGPR pressure. 34 KB -> 4 blocks/CU,
// regs < 256 -> 2 waves/SIMD (8 waves/CU) to hide the serial Thomas chain.
// launch_bounds back to (128,1): R1 evidence = clean 220-VGPR allocation;
// (128,2) evidence = arch/AGPR split pathology.
//
// Spill discipline: r never address-taken, all r indices compile-time
// (template<int OFF> halves, wave-uniform branches), float4 only on LDS.

#define EPSF 1e-6f
#define TW 68   // tile row stride (floats): rows 16B-aligned (272 B), banks even

__device__ float g_FG[30 * 256];   // per substep: F[128] then G[128]

// One block per substep s (0..29). coeff = smooth3(clip(base+lin*t+quad*t^2, EPS))*dt,
// then Thomas factorization: F_i = 1/dn_i, G_i = coeff_i/dn_i (cs_i = -G_i).
__global__ void factor_kernel(const float* __restrict__ abx,
                              const float* __restrict__ atx,
                              const float* __restrict__ aqx,
                              const float* __restrict__ bby,
                              const float* __restrict__ bty,
                              const float* __restrict__ bqy) {
  const int s = blockIdx.x;        // 0..29
  const int i = threadIdx.x;       // 0..127
  const int step = s / 3, phase = s - 3 * step;
  const float t  = 0.005f * (float)(2 * step + phase);
  const float dt = (phase == 1) ? 0.01f : 0.005f;
  const float* vb = (phase == 1) ? bby : abx;
  const float* vl = (phase == 1) ? bty : atx;
  const float* vq = (phase == 1) ? bqy : aqx;

  __shared__ float vv[128];
  __shared__ float cf[128];

  float v = vb[i] + vl[i] * t + vq[i] * t * t;
  v = fmaxf(v, EPSF);
  vv[i] = v;
  __syncthreads();
  float lft = vv[(i == 0)   ? 0   : (i - 1)];
  float rgt = vv[(i == 127) ? 127 : (i + 1)];
  cf[i] = (lft + v + rgt) * (1.0f / 3.0f) * dt;
  __syncthreads();

  if (i == 0) {
    float* Fo = g_FG + s * 256;
    float* Go = Fo + 128;
    float c0 = cf[0];
    float denom = 1.0f + c0 + EPSF;   // b[0] = 1 + coeff[0], + EPS
    float f = 1.0f / denom;
    float g = c0 * f;
    Fo[0] = f; Go[0] = g;
    float cs = -g;                    // cs_0 = c0/denom0
    for (int k = 1; k < 128; k++) {
      float ck = cf[k];
      float b  = (k == 127) ? (1.0f + ck) : (1.0f + 2.0f * ck);
      float dn = b + ck * cs + EPSF;  // b - a*cs + EPS, a = -coeff
      float fk = 1.0f / dn;
      float gk = ck * fk;
      Fo[k] = fk; Go[k] = gk;
      cs = -gk;
    }
  }
}

// Thomas substitution on a line held in registers.
// fwd: ds_i = d_i*F_i + G_i*ds_{i-1};  bwd: x_i = ds_i + G_i*x_{i+1}
__device__ __forceinline__ void solve_line(float (&r)[128],
                                           const float* __restrict__ Fs,
                                           const float* __restrict__ Gs) {
  r[0] *= Fs[0];
  #pragma unroll
  for (int i = 1; i < 128; i++) r[i] = fmaf(Gs[i], r[i - 1], r[i] * Fs[i]);
  #pragma unroll
  for (int i = 126; i >= 0; i--) r[i] = fmaf(Gs[i], r[i + 1], r[i]);
}

// Write r[OFF..OFF+63] as this lane's tile row (b128, 16B-aligned).
template <int OFF>
__device__ __forceinline__ void wr64(const float (&r)[128],
                                     float* __restrict__ b, int lane) {
  #pragma unroll
  for (int q = 0; q < 16; q++) {
    float4 t;
    t.x = r[OFF + 4*q + 0]; t.y = r[OFF + 4*q + 1];
    t.z = r[OFF + 4*q + 2]; t.w = r[OFF + 4*q + 3];
    *(float4*)&b[lane * TW + 4*q] = t;
  }
}

// Read tile column `lane` into r[OFF..OFF+63] (b32, 2-way banks = free).
template <int OFF>
__device__ __forceinline__ void rd64(float (&r)[128],
                                     const float* __restrict__ b, int lane) {
  #pragma unroll
  for (int j = 0; j < 64; j++) r[OFF + j] = b[j * TW + lane];
}

// In-place 128x128 ownership flip (rows<->cols), stash-free.
// W0 = threads 0..63 (diag block A = r[0..63]), W1 = 64..127 (diag D = r[64..127]).
// Phase A: each wave writes its diagonal block to its own tile.
// Phase B: each wave reads its transposed diagonal into the freed slots, then
//          writes its off-diagonal block to its own tile.
// Phase C: each wave reads the OTHER wave's tile -> swapped+transposed block.
// Barriers between every LDS write->read crossing (no DS-ordering assumptions).
__device__ __forceinline__ void transpose_swap(float (&r)[128],
                                               float* bufLo, float* bufHi,
                                               int tid) {
  const int lane = tid & 63;
  const bool hiw = tid >= 64;
  float* mine        = hiw ? bufHi : bufLo;
  const float* other = hiw ? bufLo : bufHi;

  __syncthreads();                         // prior consumers done with tiles
  if (!hiw) wr64<0 >(r, mine, lane); else wr64<64>(r, mine, lane);
  __syncthreads();
  if (!hiw) rd64<0 >(r, mine, lane); else rd64<64>(r, mine, lane);
  __syncthreads();                         // own-tile reads done before rewrite
  if (!hiw) wr64<64>(r, mine, lane); else wr64<0 >(r, mine, lane);
  __syncthreads();
  if (!hiw) rd64<64>(r, other, lane); else rd64<0 >(r, other, lane);
}

__global__ __launch_bounds__(128, 1) void diffusion_kernel(
    const float* __restrict__ uin,
    float* __restrict__ uout) {
  __shared__ float tiles[2 * 64 * TW] __attribute__((aligned(16)));  // 34816 B -> 4 blocks/CU
  float* bufLo = tiles;
  float* bufHi = tiles + 64 * TW;
  const int tid = threadIdx.x;
  const long long ibase = (long long)blockIdx.x << 14;   // 16384 elems per image

  float r[128];

  // ---- load row tid (per-thread contiguous float4) ----
  {
    const float* gin = uin + ibase + tid * 128;
    #pragma unroll
    for (int q = 0; q < 32; q++) {
      float4 t = *(const float4*)(gin + 4*q);
      r[4*q+0] = t.x; r[4*q+1] = t.y; r[4*q+2] = t.z; r[4*q+3] = t.w;
    }
  }

  // substep sequence: x(s=0); per step k: y(s=3k+1); x(s=3k+2) merged with
  // x(s=3k+3) for k<9 (identical t -> identical factors).
  solve_line(r, g_FG, g_FG + 128);         // x, s=0 (row ownership)
  transpose_swap(r, bufLo, bufHi, tid);    // rows -> cols

  #pragma unroll 1
  for (int k = 0; k < 10; k++) {
    const float* FGy = g_FG + (3 * k + 1) * 256;
    solve_line(r, FGy, FGy + 128);         // y (col ownership)
    transpose_swap(r, bufLo, bufHi, tid);  // cols -> rows
    const float* FGx = g_FG + (3 * k + 2) * 256;
    solve_line(r, FGx, FGx + 128);         // x, s=3k+2
    if (k < 9) {
      solve_line(r, FGx, FGx + 128);       // merged x, s=3k+3 (same factors)
      transpose_swap(r, bufLo, bufHi, tid);// rows -> cols for next y
    }
  }

  // ---- store row tid ----
  {
    float* gout = uout + ibase + tid * 128;
    #pragma unroll
    for (int q = 0; q < 32; q++) {
      float4 t;
      t.x = r[4*q+0]; t.y = r[4*q+1]; t.z = r[4*q+2]; t.w = r[4*q+3];
      *(float4*)(gout + 4*q) = t;
    }
  }
}

extern "C" void kernel_launch(void* const* d_in, const int* in_sizes, int n_in,
                              void* d_out, int out_size, void* d_ws, size_t ws_size,
                              hipStream_t stream) {
  const float* u   = (const float*)d_in[0];
  const float* abx = (const float*)d_in[1];
  const float* bby = (const float*)d_in[4];
  const float* atx = (const float*)d_in[5];
  const float* bty = (const float*)d_in[8];
  const float* aqx = (const float*)d_in[9];
  const float* bqy = (const float*)d_in[12];
  float* out = (float*)d_out;

  factor_kernel<<<30, 128, 0, stream>>>(abx, atx, aqx, bby, bty, bqy);
  diffusion_kernel<<<2048, 128, 0, stream>>>(u, out);
}

// Round 4
// 515.746 us; speedup vs baseline: 8.2379x; 8.2379x over previous
//
#include <hip/hip_runtime.h>

// ADI diffusion: 2048 images of 128x128 fp32, 10 steps of (x half, y full,
// x half) tridiagonal solves. Factorizations precomputed per substep into
// g_FG by factor_kernel.
//
// R4: named-register image. R3's float r[128] (live across the k-loop,
// accessed under divergent if/else through reference-taking helpers) was
// never promoted by SROA -> every access scratch -> 6.2 GB writes, 4171 us.
// Now the image is 32 NAMED float4 variables (R0..R31); all solve/transpose
// accesses are macro-generated with compile-time component names. No alloca
// exists, so there is nothing to fail to promote (GEMM-accumulator pattern).
// Transpose: stash-free 2x 64x68 diagonal-tile scheme (peak pressure ~180
// floats incl. working set). Wave id hoisted to SGPR via readfirstlane so
// per-wave branches are scalar; barriers stay block-uniform outside them.
// launch_bounds(128,2) caps VGPR at 256 -> with 34 KiB LDS: 4 blocks/CU =
// 8 waves/CU = 2 waves/SIMD (R1 had 1), so Thomas chains of one block hide
// under LDS phases of another.

#define EPSF 1e-6f
#define TW 68   // tile row stride (floats): rows 272 B (16B-aligned), even banks

__device__ float g_FG[30 * 256];   // per substep: F[128] then G[128]

// One block per substep s (0..29). coeff = smooth3(clip(base+lin*t+quad*t^2, EPS))*dt,
// then Thomas factorization: F_i = 1/dn_i, G_i = coeff_i/dn_i (cs_i = -G_i).
__global__ void factor_kernel(const float* __restrict__ abx,
                              const float* __restrict__ atx,
                              const float* __restrict__ aqx,
                              const float* __restrict__ bby,
                              const float* __restrict__ bty,
                              const float* __restrict__ bqy) {
  const int s = blockIdx.x;        // 0..29
  const int i = threadIdx.x;       // 0..127
  const int step = s / 3, phase = s - 3 * step;
  const float t  = 0.005f * (float)(2 * step + phase);
  const float dt = (phase == 1) ? 0.01f : 0.005f;
  const float* vb = (phase == 1) ? bby : abx;
  const float* vl = (phase == 1) ? bty : atx;
  const float* vq = (phase == 1) ? bqy : aqx;

  __shared__ float vv[128];
  __shared__ float cf[128];

  float v = vb[i] + vl[i] * t + vq[i] * t * t;
  v = fmaxf(v, EPSF);
  vv[i] = v;
  __syncthreads();
  float lft = vv[(i == 0)   ? 0   : (i - 1)];
  float rgt = vv[(i == 127) ? 127 : (i + 1)];
  cf[i] = (lft + v + rgt) * (1.0f / 3.0f) * dt;
  __syncthreads();

  if (i == 0) {
    float* Fo = g_FG + s * 256;
    float* Go = Fo + 128;
    float c0 = cf[0];
    float denom = 1.0f + c0 + EPSF;   // b[0] = 1 + coeff[0], + EPS
    float f = 1.0f / denom;
    float g = c0 * f;
    Fo[0] = f; Go[0] = g;
    float cs = -g;                    // cs_0 = c0/denom0
    for (int k = 1; k < 128; k++) {
      float ck = cf[k];
      float b  = (k == 127) ? (1.0f + ck) : (1.0f + 2.0f * ck);
      float dn = b + ck * cs + EPSF;  // b - a*cs + EPS, a = -coeff
      float fk = 1.0f / dn;
      float gk = ck * fk;
      Fo[k] = fk; Go[k] = gk;
      cs = -gk;
    }
  }
}

// ---- Thomas solve over named quads ----
// fwd: r[i] = G[i]*r[i-1] + r[i]*F[i]   (r[0] *= F[0])
// bwd: r[i] = G[i]*r[i+1] + r[i]        (i = 126..0)
#define FQ(q, p) \
  R##q.x = fmaf(Gc[4*q+0], p.w,    R##q.x * Fc[4*q+0]); \
  R##q.y = fmaf(Gc[4*q+1], R##q.x, R##q.y * Fc[4*q+1]); \
  R##q.z = fmaf(Gc[4*q+2], R##q.y, R##q.z * Fc[4*q+2]); \
  R##q.w = fmaf(Gc[4*q+3], R##q.z, R##q.w * Fc[4*q+3]);

#define BQ(q, n) \
  R##q.w = fmaf(Gc[4*q+3], n.x,    R##q.w); \
  R##q.z = fmaf(Gc[4*q+2], R##q.w, R##q.z); \
  R##q.y = fmaf(Gc[4*q+1], R##q.z, R##q.y); \
  R##q.x = fmaf(Gc[4*q+0], R##q.y, R##q.x);

#define SOLVE(FGP) { \
  const float* Fc = (FGP); const float* Gc = Fc + 128; \
  R0.x = R0.x * Fc[0]; \
  R0.y = fmaf(Gc[1], R0.x, R0.y * Fc[1]); \
  R0.z = fmaf(Gc[2], R0.y, R0.z * Fc[2]); \
  R0.w = fmaf(Gc[3], R0.z, R0.w * Fc[3]); \
  FQ(1,R0)  FQ(2,R1)  FQ(3,R2)  FQ(4,R3)  FQ(5,R4)  FQ(6,R5)  FQ(7,R6) \
  FQ(8,R7)  FQ(9,R8)  FQ(10,R9) FQ(11,R10) FQ(12,R11) FQ(13,R12) \
  FQ(14,R13) FQ(15,R14) FQ(16,R15) FQ(17,R16) FQ(18,R17) FQ(19,R18) \
  FQ(20,R19) FQ(21,R20) FQ(22,R21) FQ(23,R22) FQ(24,R23) FQ(25,R24) \
  FQ(26,R25) FQ(27,R26) FQ(28,R27) FQ(29,R28) FQ(30,R29) FQ(31,R30) \
  R31.z = fmaf(Gc[126], R31.w, R31.z); \
  R31.y = fmaf(Gc[125], R31.z, R31.y); \
  R31.x = fmaf(Gc[124], R31.y, R31.x); \
  BQ(30,R31) BQ(29,R30) BQ(28,R29) BQ(27,R28) BQ(26,R27) BQ(25,R26) \
  BQ(24,R25) BQ(23,R24) BQ(22,R23) BQ(21,R22) BQ(20,R21) BQ(19,R20) \
  BQ(18,R19) BQ(17,R18) BQ(16,R17) BQ(15,R16) BQ(14,R15) BQ(13,R14) \
  BQ(12,R13) BQ(11,R12) BQ(10,R11) BQ(9,R10)  BQ(8,R9)  BQ(7,R8) \
  BQ(6,R7)  BQ(5,R6)  BQ(4,R5)  BQ(3,R4)  BQ(2,R3)  BQ(1,R2)  BQ(0,R1) \
}

// ---- transpose primitives on named quads ----
// WRQ: lane's quad q -> own tile row `lane`, cols 4*(q mod 16) (b128, aligned).
// RDQ: tile column `lane`, rows 4*(q mod 16)+c -> quad q components (b32, 2-way).
#define WRQ(q) *(float4*)&mine[lane * TW + 4*((q)&15)] = R##q;
#define RDQ(q, b) \
  R##q.x = (b)[(4*((q)&15)+0)*TW + lane]; \
  R##q.y = (b)[(4*((q)&15)+1)*TW + lane]; \
  R##q.z = (b)[(4*((q)&15)+2)*TW + lane]; \
  R##q.w = (b)[(4*((q)&15)+3)*TW + lane];

#define WR_LO  { WRQ(0) WRQ(1) WRQ(2) WRQ(3) WRQ(4) WRQ(5) WRQ(6) WRQ(7) \
                 WRQ(8) WRQ(9) WRQ(10) WRQ(11) WRQ(12) WRQ(13) WRQ(14) WRQ(15) }
#define WR_HI  { WRQ(16) WRQ(17) WRQ(18) WRQ(19) WRQ(20) WRQ(21) WRQ(22) WRQ(23) \
                 WRQ(24) WRQ(25) WRQ(26) WRQ(27) WRQ(28) WRQ(29) WRQ(30) WRQ(31) }
#define RD_LO(b) { RDQ(0,b) RDQ(1,b) RDQ(2,b) RDQ(3,b) RDQ(4,b) RDQ(5,b) RDQ(6,b) RDQ(7,b) \
                   RDQ(8,b) RDQ(9,b) RDQ(10,b) RDQ(11,b) RDQ(12,b) RDQ(13,b) RDQ(14,b) RDQ(15,b) }
#define RD_HI(b) { RDQ(16,b) RDQ(17,b) RDQ(18,b) RDQ(19,b) RDQ(20,b) RDQ(21,b) RDQ(22,b) RDQ(23,b) \
                   RDQ(24,b) RDQ(25,b) RDQ(26,b) RDQ(27,b) RDQ(28,b) RDQ(29,b) RDQ(30,b) RDQ(31,b) }

// In-place 128x128 ownership flip (rows<->cols), stash-free, W0/W1 symmetric
// roles via diagonal (own-tile) + off-diagonal (cross-tile) blocks.
// All barriers are block-uniform, outside the scalar per-wave branches.
#define TRANSPOSE { \
  __syncthreads();                                         /* tiles free */ \
  if (w == 0) { WR_LO } else { WR_HI }                     /* diag blocks A,D */ \
  __syncthreads(); \
  if (w == 0) { RD_LO(mine) } else { RD_HI(mine) }        /* A^T, D^T */ \
  __syncthreads(); \
  if (w == 0) { WR_HI } else { WR_LO }                    /* off-diag B,C */ \
  __syncthreads(); \
  if (w == 0) { RD_HI(other) } else { RD_LO(other) }      /* C^T, B^T */ \
}

__global__ __launch_bounds__(128, 2) void diffusion_kernel(
    const float* __restrict__ uin,
    float* __restrict__ uout) {
  __shared__ float tiles[2 * 64 * TW] __attribute__((aligned(16)));  // 34816 B -> 4 blocks/CU
  const int tid  = threadIdx.x;
  const int lane = tid & 63;
  const int w    = __builtin_amdgcn_readfirstlane(tid >> 6);   // wave id, SGPR
  float* mine        = tiles + w * (64 * TW);
  const float* other = tiles + (1 - w) * (64 * TW);
  const long long ibase = (long long)blockIdx.x << 14;   // 16384 elems per image

  float4 R0, R1, R2, R3, R4, R5, R6, R7, R8, R9, R10, R11, R12, R13, R14, R15,
         R16, R17, R18, R19, R20, R21, R22, R23, R24, R25, R26, R27, R28, R29,
         R30, R31;

  // ---- load row tid (32x global_load_dwordx4, per-thread contiguous) ----
  {
    const float4* g4 = (const float4*)(uin + ibase + tid * 128);
    R0  = g4[0];  R1  = g4[1];  R2  = g4[2];  R3  = g4[3];
    R4  = g4[4];  R5  = g4[5];  R6  = g4[6];  R7  = g4[7];
    R8  = g4[8];  R9  = g4[9];  R10 = g4[10]; R11 = g4[11];
    R12 = g4[12]; R13 = g4[13]; R14 = g4[14]; R15 = g4[15];
    R16 = g4[16]; R17 = g4[17]; R18 = g4[18]; R19 = g4[19];
    R20 = g4[20]; R21 = g4[21]; R22 = g4[22]; R23 = g4[23];
    R24 = g4[24]; R25 = g4[25]; R26 = g4[26]; R27 = g4[27];
    R28 = g4[28]; R29 = g4[29]; R30 = g4[30]; R31 = g4[31];
  }

  // substep sequence: x(s=0); per step k: y(s=3k+1); x(s=3k+2) merged with
  // x(s=3k+3) for k<9 (identical t -> identical factors).
  SOLVE(g_FG)                          // x, s=0 (row ownership)
  TRANSPOSE                            // rows -> cols

  #pragma unroll 1
  for (int k = 0; k < 10; k++) {
    const float* FGy = g_FG + (3 * k + 1) * 256;
    SOLVE(FGy)                         // y (col ownership)
    TRANSPOSE                          // cols -> rows
    const float* FGx = g_FG + (3 * k + 2) * 256;
    SOLVE(FGx)                         // x, s=3k+2
    if (k < 9) {
      SOLVE(FGx)                       // merged x, s=3k+3 (same factors)
      TRANSPOSE                        // rows -> cols for next y
    }
  }

  // ---- store row tid ----
  {
    float4* g4 = (float4*)(uout + ibase + tid * 128);
    g4[0]  = R0;  g4[1]  = R1;  g4[2]  = R2;  g4[3]  = R3;
    g4[4]  = R4;  g4[5]  = R5;  g4[6]  = R6;  g4[7]  = R7;
    g4[8]  = R8;  g4[9]  = R9;  g4[10] = R10; g4[11] = R11;
    g4[12] = R12; g4[13] = R13; g4[14] = R14; g4[15] = R15;
    g4[16] = R16; g4[17] = R17; g4[18] = R18; g4[19] = R19;
    g4[20] = R20; g4[21] = R21; g4[22] = R22; g4[23] = R23;
    g4[24] = R24; g4[25] = R25; g4[26] = R26; g4[27] = R27;
    g4[28] = R28; g4[29] = R29; g4[30] = R30; g4[31] = R31;
  }
}

extern "C" void kernel_launch(void* const* d_in, const int* in_sizes, int n_in,
                              void* d_out, int out_size, void* d_ws, size_t ws_size,
                              hipStream_t stream) {
  const float* u   = (const float*)d_in[0];
  const float* abx = (const float*)d_in[1];
  const float* bby = (const float*)d_in[4];
  const float* atx = (const float*)d_in[5];
  const float* bty = (const float*)d_in[8];
  const float* aqx = (const float*)d_in[9];
  const float* bqy = (const float*)d_in[12];
  float* out = (float*)d_out;

  factor_kernel<<<30, 128, 0, stream>>>(abx, atx, aqx, bby, bty, bqy);
  diffusion_kernel<<<2048, 128, 0, stream>>>(u, out);
}